// Round 8
// baseline (174.332 us; speedup 1.0000x reference)
//
#include <hip/hip_runtime.h>
#include <stdint.h>

// Volterra layer: out = conv3x3(x,w1) + conv3x3(quad,w2) + (b1 + 4*b2)
// quad = sum over 4 shifts of clip(x * circular_shift(x), -1, 1)
// B=8, C=64, H=W=256. Convs are zero-pad SAME; shifts are circular.

typedef short s16x8 __attribute__((ext_vector_type(8)));
typedef float f32x4 __attribute__((ext_vector_type(4)));

__device__ __forceinline__ float clip1(float v) { return fminf(fmaxf(v, -1.f), 1.f); }

__device__ __forceinline__ unsigned short f2bf(float f) {
    union { float f; unsigned u; } v; v.f = f;
    unsigned u = v.u;
    return (unsigned short)((u + 0x7fffu + ((u >> 16) & 1u)) >> 16);
}

__device__ __forceinline__ float bf2f(unsigned short u) {
    union { unsigned v; float f; } t; t.v = ((unsigned)u) << 16; return t.f;
}

// async global->LDS, 16B per lane; lds dest is wave-uniform base + lane*16
__device__ __forceinline__ void gload16(const void* g, void* l) {
    __builtin_amdgcn_global_load_lds(
        (const __attribute__((address_space(1))) unsigned int*)g,
        (__attribute__((address_space(3))) unsigned int*)l, 16, 0, 0);
}

// ---------------------------------------------------------------------------
// Kernel 1: weights -> bf16, layout Wb[kh][cc][co][kw*32+cci]
// ---------------------------------------------------------------------------
__global__ void prep_w(const float* __restrict__ w1, const float* __restrict__ w2,
                       unsigned short* __restrict__ Wb) {
    int idx = blockIdx.x * 256 + threadIdx.x;   // exactly 73728 threads
    int kk = idx % 96;
    int rest = idx / 96;
    int co = rest & 63; rest >>= 6;
    int cc = rest & 3;
    int kh = rest >> 2;
    int kw = kk >> 5;
    int cci = kk & 31;
    int c2 = cc * 32 + cci;
    const float* src = (c2 < 64) ? w1 : w2;
    int ci = c2 & 63;
    Wb[idx] = f2bf(src[((co * 64 + ci) * 3 + kh) * 3 + kw]);
}

// ---------------------------------------------------------------------------
// Kernel 2: LDS-transposed quad/pack (R2 version -- at HBM floor ~61us).
// U[(b*256+h)*256+w][c2]: c2 0-63 = bf16(x), 64-127 = bf16(quad).
// ---------------------------------------------------------------------------
__global__ __launch_bounds__(512, 1) void prep_u2(const float* __restrict__ x,
                                                  unsigned short* __restrict__ U) {
    __shared__ unsigned short X[3][64][268];
    int bid = blockIdx.x;
    int bh = ((bid & 7) << 8) + (bid >> 3);   // XCD k -> batch image k
    int b = bh >> 8, h = bh & 255;
    int tid = threadIdx.x;

    for (int it = 0; it < 24; ++it) {
        int idx = tid + (it << 9);
        int w4 = idx & 63;
        int c  = (idx >> 6) & 63;
        int r  = idx >> 12;
        int gr = (h + r + 255) & 255;
        const float4 v = *(const float4*)(x + (((size_t)(b * 64 + c)) << 16)
                                            + (gr << 8) + (w4 << 2));
        ushort4 p;
        p.x = f2bf(v.x); p.y = f2bf(v.y); p.z = f2bf(v.z); p.w = f2bf(v.w);
        *(ushort4*)&X[r][c][w4 << 2] = p;
    }
    __syncthreads();

    int c  = tid & 63;
    int wv = tid >> 6;
    int p0 = wv << 5;
    int pm0 = (p0 + 255) & 255;
    float pxc = bf2f(X[1][c][pm0]);
    float pxu = bf2f(X[0][c][pm0]);
    float pxd = bf2f(X[2][c][pm0]);
    size_t base = ((size_t)bh) << 8;
#pragma unroll 4
    for (int i = 0; i < 32; ++i) {
        int p = p0 + i;
        unsigned short xcb = X[1][c][p];
        float xc = bf2f(xcb);
        float xu = bf2f(X[0][c][p]);
        float xd = bf2f(X[2][c][p]);
        float q = clip1(xc * xu) + clip1(xc * pxd) + clip1(xc * pxc) + clip1(xc * pxu);
        size_t po = (base + p) << 7;
        U[po + c]      = xcb;
        U[po + 64 + c] = f2bf(q);
        pxc = xc; pxu = xu; pxd = xd;
    }
}

// ---------------------------------------------------------------------------
// Kernel 3 (v6): fat-stage implicit-GEMM conv.
// Block = 4 output rows x 128 px, 512 thr = 8 waves (rowsel 0..3 x pq 0..1).
// Per cc-chunk (32 ch): ALL 6 input rows h0-1..h0+4 staged (double-buffered)
// + weights for 3 kh (single-buffered), both via global_load_lds width=16
// into UNPADDED linear LDS (strides 32/96 shorts: uniform 8 dwords/bank for
// the b128 reads = conflict floor). One compute phase per cc: 144 mfma/wave,
// 100% duty (edge rows zero-filled -> contribute 0 = zero-pad semantics).
// 2 barriers per cc (8 total vs conv5's 24). Input prefetch issued before
// compute; its latency hides under ~6k cyc of MFMA+ds_read.
// LDS 136.7 KB -> 1 block/CU (8 waves); pipe-bound not latency-bound.
// ---------------------------------------------------------------------------
__global__ __launch_bounds__(512, 2) void conv6(
        const unsigned short* __restrict__ U,
        const unsigned short* __restrict__ Wb,
        const float* __restrict__ b1, const float* __restrict__ b2,
        float* __restrict__ out) {
    __shared__ unsigned short Alds[3][64][96];      // 36864 B, linear
    __shared__ unsigned short Ib[2][6][130][32];    // 99840 B, linear

    int bid = blockIdx.x;                          // 1024 blocks
    int logical = ((bid & 7) << 7) + (bid >> 3);   // XCD k -> batch image k
    int b = logical >> 7;
    int rem = logical & 127;
    int h0 = (rem >> 1) << 2;                      // 4 output rows h0..h0+3
    int whalf = rem & 1;
    int w0 = whalf << 7;
    int tid = threadIdx.x;
    int wid = tid >> 6;
    int ln = tid & 63;
    int lr = ln & 15;        // MFMA A-row / C col
    int lq = ln >> 4;        // MFMA k-group / C row-group
    int rowsel = wid >> 1;   // which of the 4 output rows
    int pq = wid & 1;        // pixel 64-half within the 128-px half
    int o = h0 + rowsel;

    const size_t ubase = ((size_t)b) << 23;

    f32x4 acc[4][4];
#pragma unroll
    for (int m = 0; m < 4; m++)
#pragma unroll
        for (int n = 0; n < 4; n++) {
            acc[m][n][0] = 0.f; acc[m][n][1] = 0.f; acc[m][n][2] = 0.f; acc[m][n][3] = 0.f;
        }

    // ---- staging helpers -------------------------------------------------
    // interior input: rows ir 0..5 (global r=h0-1+ir), px p=1..128, 32ch.
    // one global_load_lds per wave per ir (64 lanes x 16B = one 512-uint4 row
    // covered by the block's 8 waves).
    auto stage_input = [&](int ccx, int nb) {
        const unsigned short* ub = U + ubase + ccx * 32;
#pragma unroll
        for (int ir = 0; ir < 6; ++ir) {
            int r = h0 - 1 + ir;
            if (r < 0 || r > 255) continue;               // block-uniform
            int p = 1 + (tid >> 2), q = tid & 3;
            const unsigned short* g = ub + (((size_t)r) << 15)
                                        + (((size_t)(w0 + p - 1)) << 7) + q * 8;
            unsigned short* l = &Ib[nb][ir][1][0] + (size_t)wid * 512;  // wave-uniform
            gload16(g, l);
        }
    };
    // weights: 2304 uint4 = 4.5 rounds; round 4 uses waves 0-3 only (uniform).
    auto stage_weights = [&](int ccx) {
#pragma unroll
        for (int k = 0; k < 5; ++k) {
            int J = k * 512 + tid;
            if (J < 2304) {
                int kh = J / 768;
                int remw = J - kh * 768;
                const unsigned short* g = Wb + (size_t)(kh * 4 + ccx) * 6144 + remw * 8;
                unsigned short* l = ((unsigned short*)Alds) + (size_t)(k * 512 + wid * 64) * 8;
                gload16(g, l);
            }
        }
    };
    // halo px (p=0,129) + zero-fill for out-of-range rows.
    auto fix_edges = [&](int ccx, int nb) {
        if (tid < 48) {
            int ir = tid >> 3, rest = tid & 7;
            int side = rest >> 2, q = rest & 3;
            int p = side ? 129 : 0;
            int gcol = side ? (w0 + 128) : (w0 - 1);
            int r = h0 - 1 + ir;
            uint4 v = make_uint4(0u, 0u, 0u, 0u);
            if (gcol >= 0 && gcol <= 255 && r >= 0 && r <= 255)
                v = *(const uint4*)(U + ubase + (((size_t)r) << 15)
                                    + (((size_t)gcol) << 7) + ccx * 32 + q * 8);
            *(uint4*)&Ib[nb][ir][p][q * 8] = v;
        }
        if (h0 == 0)
            for (int i = tid; i < 520; i += 512)
                *(uint4*)&Ib[nb][0][i >> 2][(i & 3) * 8] = make_uint4(0u, 0u, 0u, 0u);
        if (h0 == 252)
            for (int i = tid; i < 520; i += 512)
                *(uint4*)&Ib[nb][5][i >> 2][(i & 3) * 8] = make_uint4(0u, 0u, 0u, 0u);
    };

    // ---- prologue: stage cc=0 --------------------------------------------
    stage_input(0, 0);
    stage_weights(0);
    fix_edges(0, 0);
    __syncthreads();   // drains gload_lds (vmcnt) + ds_writes (lgkm)

    int cur = 0;
    for (int cc = 0; cc < 4; ++cc) {
        if (cc < 3) stage_input(cc + 1, cur ^ 1);   // in flight under compute
        __builtin_amdgcn_s_setprio(1);
#pragma unroll
        for (int kh = 0; kh < 3; ++kh) {
            int ir = rowsel + kh;
#pragma unroll
            for (int kw = 0; kw < 3; ++kw) {
                s16x8 af[4], bfr[4];
#pragma unroll
                for (int m = 0; m < 4; m++)
                    af[m] = *(const s16x8*)&Alds[kh][m * 16 + lr][kw * 32 + lq * 8];
#pragma unroll
                for (int n = 0; n < 4; n++)
                    bfr[n] = *(const s16x8*)&Ib[cur][ir][(pq << 6) + n * 16 + lr + kw][lq * 8];
#pragma unroll
                for (int m = 0; m < 4; m++)
#pragma unroll
                    for (int n = 0; n < 4; n++)
                        acc[m][n] = __builtin_amdgcn_mfma_f32_16x16x32_bf16(af[m], bfr[n], acc[m][n], 0, 0, 0);
            }
        }
        __builtin_amdgcn_s_setprio(0);
        __syncthreads();                 // done reading Alds(cc)+Ib[cur]; input(cc+1) landed
        if (cc < 3) {
            stage_weights(cc + 1);       // ~300-500 cyc L2 latency, only exposed stall
            fix_edges(cc + 1, cur ^ 1);
            __syncthreads();             // publish
            cur ^= 1;
        }
    }

    // ---- epilogue: C/D layout col=lane&15 (pixel), row=(lane>>4)*4+jj (cout)
#pragma unroll
    for (int m = 0; m < 4; m++) {
#pragma unroll
        for (int jj = 0; jj < 4; jj++) {
            int co = m * 16 + lq * 4 + jj;
            float bias = b1[co] + 4.f * b2[co];
#pragma unroll
            for (int n = 0; n < 4; n++) {
                int wpix = w0 + (pq << 6) + n * 16 + lr;
                out[(((size_t)(b * 64 + co)) << 16) + (o << 8) + wpix] = acc[m][n][jj] + bias;
            }
        }
    }
}

// ---------------------------------------------------------------------------
// Fallback (only if ws too small): direct conv, recomputing quad on the fly.
// ---------------------------------------------------------------------------
__global__ void fallback_conv(const float* __restrict__ x,
                              const float* __restrict__ w1, const float* __restrict__ b1,
                              const float* __restrict__ w2, const float* __restrict__ b2,
                              float* __restrict__ out) {
    size_t idx = (size_t)blockIdx.x * 256 + threadIdx.x;
    int w = idx & 255;
    int h = (int)(idx >> 8) & 255;
    int co = (int)(idx >> 16) & 63;
    int b = (int)(idx >> 22);
    float acc = b1[co] + 4.f * b2[co];
    const float* xb = x + (((size_t)b * 64) << 16);
    for (int ci = 0; ci < 64; ci++) {
        const float* xp = xb + (((size_t)ci) << 16);
        for (int kh = 0; kh < 3; kh++) {
            int hh = h + kh - 1;
            if (hh < 0 || hh > 255) continue;
            for (int kw = 0; kw < 3; kw++) {
                int ww = w + kw - 1;
                if (ww < 0 || ww > 255) continue;
                float xv = xp[(hh << 8) + ww];
                float g1 = w1[((co * 64 + ci) * 3 + kh) * 3 + kw];
                float g2 = w2[((co * 64 + ci) * 3 + kh) * 3 + kw];
                int hm = (hh + 255) & 255, hp = (hh + 1) & 255, wm = (ww + 255) & 255;
                float q = clip1(xv * xp[(hm << 8) + ww]) + clip1(xv * xp[(hp << 8) + wm])
                        + clip1(xv * xp[(hh << 8) + wm]) + clip1(xv * xp[(hm << 8) + wm]);
                acc = fmaf(g1, xv, acc);
                acc = fmaf(g2, q, acc);
            }
        }
    }
    out[idx] = acc;
}

extern "C" void kernel_launch(void* const* d_in, const int* in_sizes, int n_in,
                              void* d_out, int out_size, void* d_ws, size_t ws_size,
                              hipStream_t stream) {
    const float* x  = (const float*)d_in[0];
    const float* w1 = (const float*)d_in[1];
    const float* b1 = (const float*)d_in[2];
    const float* w2 = (const float*)d_in[3];
    const float* b2 = (const float*)d_in[4];
    float* out = (float*)d_out;

    const size_t WB_BYTES = 262144;
    const size_t U_BYTES  = (size_t)8 * 256 * 256 * 128 * 2;  // 128 MiB
    if (ws_size >= WB_BYTES + U_BYTES) {
        unsigned short* Wb = (unsigned short*)d_ws;
        unsigned short* U  = (unsigned short*)((char*)d_ws + WB_BYTES);
        prep_w<<<dim3(288), dim3(256), 0, stream>>>(w1, w2, Wb);
        prep_u2<<<dim3(2048), dim3(512), 0, stream>>>(x, U);
        conv6<<<dim3(1024), dim3(512), 0, stream>>>(U, Wb, b1, b2, out);
    } else {
        fallback_conv<<<dim3(131072), dim3(256), 0, stream>>>(x, w1, b1, w2, b2, out);
    }
}

// Round 9
// 172.815 us; speedup vs baseline: 1.0088x; 1.0088x over previous
//
#include <hip/hip_runtime.h>
#include <stdint.h>

// Volterra layer: out = conv3x3(x,w1) + conv3x3(quad,w2) + (b1 + 4*b2)
// quad = sum over 4 shifts of clip(x * circular_shift(x), -1, 1)
// B=8, C=64, H=W=256. Convs are zero-pad SAME; shifts are circular.

typedef short s16x8 __attribute__((ext_vector_type(8)));
typedef float f32x4 __attribute__((ext_vector_type(4)));

__device__ __forceinline__ float clip1(float v) { return fminf(fmaxf(v, -1.f), 1.f); }

__device__ __forceinline__ unsigned short f2bf(float f) {
    union { float f; unsigned u; } v; v.f = f;
    unsigned u = v.u;
    return (unsigned short)((u + 0x7fffu + ((u >> 16) & 1u)) >> 16);
}

__device__ __forceinline__ float bf2f(unsigned short u) {
    union { unsigned v; float f; } t; t.v = ((unsigned)u) << 16; return t.f;
}

// async global->LDS, 16B per lane; global src is PER-LANE, lds dest is
// wave-uniform base + lane*16 (linear).
__device__ __forceinline__ void gload16(const void* g, void* l) {
    __builtin_amdgcn_global_load_lds(
        (const __attribute__((address_space(1))) unsigned int*)g,
        (__attribute__((address_space(3))) unsigned int*)l, 16, 0, 0);
}

// ---------------------------------------------------------------------------
// Kernel 1: weights -> bf16 in PRE-SWIZZLED padded layout.
// Wb2[kh][cc][co][beta=0..15][8]: slot beta holds logical blk = beta^(co&7),
// blk = kw*4+lq (12 real, 4 zero-pad slots). Linear gload of a row then gives
// LDS bank = 4*((blk^lr)&7): 8 starts x 2 lanes = conflict floor.
// ---------------------------------------------------------------------------
__global__ void prep_w(const float* __restrict__ w1, const float* __restrict__ w2,
                       unsigned short* __restrict__ Wb2) {
    int idx = blockIdx.x * 256 + threadIdx.x;   // exactly 98304 threads
    int sh   = idx & 7;
    int beta = (idx >> 3) & 15;
    int co   = (idx >> 7) & 63;
    int cc   = (idx >> 13) & 3;
    int kh   = idx >> 15;                        // 0..2
    int blk  = beta ^ (co & 7);
    float val = 0.f;
    if (blk < 12) {
        int kw = blk >> 2;
        int lq = blk & 3;
        int c2 = cc * 32 + lq * 8 + sh;
        const float* src = (c2 < 64) ? w1 : w2;
        val = src[((co * 64 + (c2 & 63)) * 3 + kh) * 3 + kw];
    }
    Wb2[idx] = f2bf(val);
}

// ---------------------------------------------------------------------------
// Kernel 2: LDS-transposed quad/pack (R2 version -- at HBM floor ~61us).
// U[(b*256+h)*256+w][c2]: c2 0-63 = bf16(x), 64-127 = bf16(quad).
// ---------------------------------------------------------------------------
__global__ __launch_bounds__(512, 1) void prep_u2(const float* __restrict__ x,
                                                  unsigned short* __restrict__ U) {
    __shared__ unsigned short X[3][64][268];
    int bid = blockIdx.x;
    int bh = ((bid & 7) << 8) + (bid >> 3);   // XCD k -> batch image k
    int b = bh >> 8, h = bh & 255;
    int tid = threadIdx.x;

    for (int it = 0; it < 24; ++it) {
        int idx = tid + (it << 9);
        int w4 = idx & 63;
        int c  = (idx >> 6) & 63;
        int r  = idx >> 12;
        int gr = (h + r + 255) & 255;
        const float4 v = *(const float4*)(x + (((size_t)(b * 64 + c)) << 16)
                                            + (gr << 8) + (w4 << 2));
        ushort4 p;
        p.x = f2bf(v.x); p.y = f2bf(v.y); p.z = f2bf(v.z); p.w = f2bf(v.w);
        *(ushort4*)&X[r][c][w4 << 2] = p;
    }
    __syncthreads();

    int c  = tid & 63;
    int wv = tid >> 6;
    int p0 = wv << 5;
    int pm0 = (p0 + 255) & 255;
    float pxc = bf2f(X[1][c][pm0]);
    float pxu = bf2f(X[0][c][pm0]);
    float pxd = bf2f(X[2][c][pm0]);
    size_t base = ((size_t)bh) << 8;
#pragma unroll 4
    for (int i = 0; i < 32; ++i) {
        int p = p0 + i;
        unsigned short xcb = X[1][c][p];
        float xc = bf2f(xcb);
        float xu = bf2f(X[0][c][p]);
        float xd = bf2f(X[2][c][p]);
        float q = clip1(xc * xu) + clip1(xc * pxd) + clip1(xc * pxc) + clip1(xc * pxu);
        size_t po = (base + p) << 7;
        U[po + c]      = xcb;
        U[po + 64 + c] = f2bf(q);
        pxc = xc; pxu = xu; pxd = xd;
    }
}

// ---------------------------------------------------------------------------
// Kernel 3 (v7): fat-stage conv with conflict-FREE swizzled LDS on both paths.
// Block = 4 output rows x 128 px, 512 thr = 8 waves. Per cc-chunk: 6 input
// rows double-buffered + 3-kh weights single-buffered, all via gload16 with
// per-lane pre-swizzled GLOBAL source + linear LDS dest (rule #21).
//   A phys: Alds[kh][co][slot*8], slot = (kw*4+lq) ^ (co&7)  (baked into Wb2)
//   B phys: Ib[nb][ir] byte = (p>>1)*128 + s*16, s = ((p&1)*4|lq) ^ ((p>>1)&7)
// Both: 8 bank-starts x 2 lanes per 16-lane phase = b128 conflict floor.
// Halo p=0/129 -> phys bytes [0,64) / [8256,8320): outside gload range.
// ---------------------------------------------------------------------------
__global__ __launch_bounds__(512, 2) void conv7(
        const unsigned short* __restrict__ U,
        const unsigned short* __restrict__ Wb2,
        const float* __restrict__ b1, const float* __restrict__ b2,
        float* __restrict__ out) {
    __shared__ unsigned short Alds[3][64][128];   // 49152 B
    __shared__ unsigned short Ib[2][6][4160];     // 2 x 6 x 8320 B = 99840 B

    int bid = blockIdx.x;                          // 1024 blocks
    int logical = ((bid & 7) << 7) + (bid >> 3);   // XCD k -> batch image k
    int b = logical >> 7;
    int rem = logical & 127;
    int h0 = (rem >> 1) << 2;                      // 4 output rows h0..h0+3
    int whalf = rem & 1;
    int w0 = whalf << 7;
    int tid = threadIdx.x;
    int wid = tid >> 6;
    int ln = tid & 63;
    int lr = ln & 15;        // MFMA A-row / C col
    int lq = ln >> 4;        // MFMA k-group / C row-group
    int rowsel = wid >> 1;   // which of the 4 output rows
    int pq = wid & 1;        // pixel 64-half within the 128-px half
    int o = h0 + rowsel;
    const size_t ubase = ((size_t)b) << 23;

    // per-lane inverse-swizzle for input staging: dest byte -> (p, lq) -> col
    int D   = 64 + wid * 1024 + ln * 16;          // dest byte within Ib[nb][ir]
    int su  = D >> 7;                             // unit
    int stv = ((D >> 4) & 7) ^ (su & 7);          // logical (rho<<2)|lq
    int sp  = 2 * su + (stv >> 2);                // logical row p (1..128)
    int slq = stv & 3;                            // channel block
    int scol = w0 - 1 + sp;                       // global col, always 0..255
    const unsigned short* usrc0 = U + ubase + (((size_t)scol) << 7) + slq * 8;

    f32x4 acc[4][4];
#pragma unroll
    for (int m = 0; m < 4; m++)
#pragma unroll
        for (int n = 0; n < 4; n++) {
            acc[m][n][0] = 0.f; acc[m][n][1] = 0.f; acc[m][n][2] = 0.f; acc[m][n][3] = 0.f;
        }

    // ---- staging helpers -------------------------------------------------
    auto stage_input = [&](int ccx, int nb) {
#pragma unroll
        for (int ir = 0; ir < 6; ++ir) {
            int r = h0 - 1 + ir;
            if (r < 0 || r > 255) continue;               // block-uniform
            const unsigned short* g = usrc0 + (((size_t)r) << 15) + ccx * 32;
            void* l = (char*)&Ib[nb][ir][0] + 64 + wid * 1024;   // wave-uniform
            gload16(g, l);
        }
    };
    auto stage_weights = [&](int ccx) {
#pragma unroll
        for (int k = 0; k < 6; ++k) {                     // 6*512*16B = 49152 B exact
            int j = k * 512 + tid;
            int kh = j >> 10;
            int remw = j & 1023;
            const unsigned short* g = Wb2 + (((size_t)(kh * 4 + ccx)) << 13) + remw * 8;
            void* l = (char*)Alds + (size_t)(k * 512 + wid * 64) * 16;
            gload16(g, l);
        }
    };
    auto fix_edges = [&](int ccx, int nb) {
        if (tid < 48) {
            int ir = tid >> 3, r2 = tid & 7;
            int side = r2 >> 2, q = r2 & 3;
            int gcol = side ? (w0 + 128) : (w0 - 1);
            int r = h0 - 1 + ir;
            uint4 v = make_uint4(0u, 0u, 0u, 0u);
            if (gcol >= 0 && gcol <= 255 && r >= 0 && r <= 255)
                v = *(const uint4*)(U + ubase + (((size_t)r) << 15)
                                    + (((size_t)gcol) << 7) + ccx * 32 + q * 8);
            int off = side ? (8192 + (4 + q) * 16) : (q * 16);  // p=129 / p=0 slots
            *(uint4*)((char*)&Ib[nb][ir][0] + off) = v;
        }
        if (h0 == 0)
            for (int i = tid; i < 520; i += 512)
                *(uint4*)((char*)&Ib[nb][0][0] + i * 16) = make_uint4(0u, 0u, 0u, 0u);
        if (h0 == 252)
            for (int i = tid; i < 520; i += 512)
                *(uint4*)((char*)&Ib[nb][5][0] + i * 16) = make_uint4(0u, 0u, 0u, 0u);
    };

    // ---- prologue: stage cc=0 --------------------------------------------
    stage_input(0, 0);
    stage_weights(0);
    fix_edges(0, 0);
    __syncthreads();

    int cur = 0;
    for (int cc = 0; cc < 4; ++cc) {
        if (cc < 3) {
            stage_input(cc + 1, cur ^ 1);   // gloads in flight under compute
            fix_edges(cc + 1, cur ^ 1);     // disjoint bytes from gload range
        }
        __builtin_amdgcn_s_setprio(1);
#pragma unroll
        for (int kh = 0; kh < 3; ++kh) {
            int ir = rowsel + kh;
            const char* ibb = (const char*)&Ib[cur][ir][0];
#pragma unroll
            for (int kw = 0; kw < 3; ++kw) {
                s16x8 af[4], bfr[4];
                int slot = ((kw << 2) | lq) ^ (lr & 7);
#pragma unroll
                for (int m = 0; m < 4; m++)
                    af[m] = *(const s16x8*)&Alds[kh][m * 16 + lr][slot * 8];
#pragma unroll
                for (int n = 0; n < 4; n++) {
                    int p = (pq << 6) + n * 16 + lr + kw;
                    int u = p >> 1;
                    int s = (((p & 1) << 2) | lq) ^ (u & 7);
                    bfr[n] = *(const s16x8*)(ibb + u * 128 + s * 16);
                }
#pragma unroll
                for (int m = 0; m < 4; m++)
#pragma unroll
                    for (int n = 0; n < 4; n++)
                        acc[m][n] = __builtin_amdgcn_mfma_f32_16x16x32_bf16(af[m], bfr[n], acc[m][n], 0, 0, 0);
            }
        }
        __builtin_amdgcn_s_setprio(0);
        __syncthreads();                 // Alds/Ib[cur] free; input(cc+1) landed
        if (cc < 3) {
            stage_weights(cc + 1);       // only exposed stall (~L2 latency)
            __syncthreads();             // publish
            cur ^= 1;
        }
    }

    // ---- epilogue: C/D layout col=lane&15 (pixel), row=(lane>>4)*4+jj (cout)
#pragma unroll
    for (int m = 0; m < 4; m++) {
#pragma unroll
        for (int jj = 0; jj < 4; jj++) {
            int co = m * 16 + lq * 4 + jj;
            float bias = b1[co] + 4.f * b2[co];
#pragma unroll
            for (int n = 0; n < 4; n++) {
                int wpix = w0 + (pq << 6) + n * 16 + lr;
                out[(((size_t)(b * 64 + co)) << 16) + (o << 8) + wpix] = acc[m][n][jj] + bias;
            }
        }
    }
}

// ---------------------------------------------------------------------------
// Fallback (only if ws too small): direct conv, recomputing quad on the fly.
// ---------------------------------------------------------------------------
__global__ void fallback_conv(const float* __restrict__ x,
                              const float* __restrict__ w1, const float* __restrict__ b1,
                              const float* __restrict__ w2, const float* __restrict__ b2,
                              float* __restrict__ out) {
    size_t idx = (size_t)blockIdx.x * 256 + threadIdx.x;
    int w = idx & 255;
    int h = (int)(idx >> 8) & 255;
    int co = (int)(idx >> 16) & 63;
    int b = (int)(idx >> 22);
    float acc = b1[co] + 4.f * b2[co];
    const float* xb = x + (((size_t)b * 64) << 16);
    for (int ci = 0; ci < 64; ci++) {
        const float* xp = xb + (((size_t)ci) << 16);
        for (int kh = 0; kh < 3; kh++) {
            int hh = h + kh - 1;
            if (hh < 0 || hh > 255) continue;
            for (int kw = 0; kw < 3; kw++) {
                int ww = w + kw - 1;
                if (ww < 0 || ww > 255) continue;
                float xv = xp[(hh << 8) + ww];
                float g1 = w1[((co * 64 + ci) * 3 + kh) * 3 + kw];
                float g2 = w2[((co * 64 + ci) * 3 + kh) * 3 + kw];
                int hm = (hh + 255) & 255, hp = (hh + 1) & 255, wm = (ww + 255) & 255;
                float q = clip1(xv * xp[(hm << 8) + ww]) + clip1(xv * xp[(hp << 8) + wm])
                        + clip1(xv * xp[(hh << 8) + wm]) + clip1(xv * xp[(hm << 8) + wm]);
                acc = fmaf(g1, xv, acc);
                acc = fmaf(g2, q, acc);
            }
        }
    }
    out[idx] = acc;
}

extern "C" void kernel_launch(void* const* d_in, const int* in_sizes, int n_in,
                              void* d_out, int out_size, void* d_ws, size_t ws_size,
                              hipStream_t stream) {
    const float* x  = (const float*)d_in[0];
    const float* w1 = (const float*)d_in[1];
    const float* b1 = (const float*)d_in[2];
    const float* w2 = (const float*)d_in[3];
    const float* b2 = (const float*)d_in[4];
    float* out = (float*)d_out;

    const size_t WB_BYTES = 262144;                       // Wb2 uses 196608
    const size_t U_BYTES  = (size_t)8 * 256 * 256 * 128 * 2;  // 128 MiB
    if (ws_size >= WB_BYTES + U_BYTES) {
        unsigned short* Wb2 = (unsigned short*)d_ws;
        unsigned short* U   = (unsigned short*)((char*)d_ws + WB_BYTES);
        prep_w<<<dim3(384), dim3(256), 0, stream>>>(w1, w2, Wb2);
        prep_u2<<<dim3(2048), dim3(512), 0, stream>>>(x, U);
        conv7<<<dim3(1024), dim3(512), 0, stream>>>(U, Wb2, b1, b2, out);
    } else {
        fallback_conv<<<dim3(131072), dim3(256), 0, stream>>>(x, w1, b1, w2, b2, out);
    }
}